// Round 4
// baseline (415.676 us; speedup 1.0000x reference)
//
#include <hip/hip_runtime.h>
#include <math.h>

#define N_NODES 32768
#define F_IN    128
#define C_CH    4
#define H_HEADS 8
#define D_DIM   32
#define DM      256
#define E_BOND  65536
#define B_BRIDGE 8192
#define ET      (E_BOND + 2*B_BRIDGE)   // 81920
#define OUTC    1024                    // C*H*D
#define CAP     24                      // bucket capacity per dst node
#define NCOLS   1280                    // DM + OUTC combined bf16 weight rows

// ---- workspace layout (bytes) ----
#define WS_XL      0u                   // N*DM*4      = 33,554,432 (f32, aggregation)
#define WS_XLB     33554432u            // N*DM*2      = 16,777,216 (bf16, scores)
#define WS_PE      50331648u            // C*DM*4      = 4,096
#define WS_BUCKET  50335744u            // N*CAP*16    = 12,582,912 (int4: nA,nB,g,tp)
#define WS_CNT     62918656u            // N*4         = 131,072
#define WS_RESID   63049728u            // N*OUTC*2    = 67,108,864 (f16 residual)
#define WS_XB      130158592u           // N*128*2     = 8,388,608
#define WS_WC      138547200u           // NCOLS*128*2 = 327,680 -> end ~138.9 MB

typedef __attribute__((ext_vector_type(8))) short bf16x8;
typedef __attribute__((ext_vector_type(4))) float f32x4;
typedef __attribute__((ext_vector_type(4))) _Float16 f16x4;

__device__ __forceinline__ float leaky(float v) { return v >= 0.f ? v : 0.2f*v; }
__device__ __forceinline__ ushort f2bf(float f) {
    unsigned u = __float_as_uint(f);
    unsigned r = (u + 0x7fffu + ((u >> 16) & 1u)) >> 16;   // RNE
    return (ushort)r;
}
__device__ __forceinline__ float bf2f(ushort u) {
    return __uint_as_float((unsigned)u << 16);
}

// decode edge e -> endpoints (nA,nB) and type
__device__ __forceinline__ void edge_decode(int e, const int* __restrict__ ei,
                                            const int* __restrict__ bi,
                                            int& nA, int& nB, int& tp) {
    if (e < E_BOND)               { nA = ei[e]; nB = ei[E_BOND + e]; tp = 0; }
    else if (e < E_BOND+B_BRIDGE) { int i = e - E_BOND;
                                    nA = bi[B_BRIDGE + i]; nB = bi[i]; tp = 1; }
    else                          { int i = e - E_BOND - B_BRIDGE;
                                    nA = bi[i]; nB = bi[B_BRIDGE + i]; tp = 2; }
}

// ---------------- pe init ----------------
__global__ void pe_init_kernel(float* __restrict__ pe) {
    int tid = threadIdx.x;              // 1024
    int c = tid >> 8, p = tid & 255;
    float expo = (float)(p & ~1) * (1.0f/256.0f);
    float div  = powf(10000.0f, expo);
    float arg  = (float)c / div;
    pe[tid] = (p & 1) ? cosf(arg) : sinf(arg);
}

// ---------------- fp32 -> bf16 converts ----------------
__global__ __launch_bounds__(256) void cvt_x_kernel(const float* __restrict__ x,
                                                    ushort* __restrict__ xb) {
    const long i = (long)blockIdx.x*256 + threadIdx.x;    // float4 index
    float4 v = ((const float4*)x)[i];
    ushort4 o; o.x = f2bf(v.x); o.y = f2bf(v.y); o.z = f2bf(v.z); o.w = f2bf(v.w);
    ((ushort4*)xb)[i] = o;
}
__global__ __launch_bounds__(256) void cvt_w_kernel(const float* __restrict__ W_in,
                                                    const float* __restrict__ W_res,
                                                    ushort* __restrict__ wc) {
    const int i = blockIdx.x*256 + threadIdx.x;           // float4 index, 40960 total
    float4 v = (i < 8192) ? ((const float4*)W_in)[i] : ((const float4*)W_res)[i - 8192];
    ushort4 o; o.x = f2bf(v.x); o.y = f2bf(v.y); o.z = f2bf(v.z); o.w = f2bf(v.w);
    ((ushort4*)wc)[i] = o;
}

// ---------------- combined MFMA GEMM over 1280 cols ----------------
// cols [0,256)   -> xl (f32) + xlb (bf16)  = x @ W_in^T
// cols [256,1280)-> resid (f16)            = x @ W_res^T
#define LDSK 72   // 64 + 8 pad (bf16)
__global__ __launch_bounds__(256) void mfma_gemm(
        const ushort* __restrict__ xb, const ushort* __restrict__ wc,
        float* __restrict__ xl, ushort* __restrict__ xlb,
        _Float16* __restrict__ resid) {
    __shared__ ushort As[128*LDSK];
    __shared__ ushort Bs[128*LDSK];
    const int tid = threadIdx.x;
    const int m0 = blockIdx.x * 128;
    const int n0 = blockIdx.y * 128;
    const int lane = tid & 63, wv = tid >> 6;
    const int wm = wv & 1, wn = wv >> 1;
    const int quad = lane >> 4, l15 = lane & 15;
    const int mbase = wm*64, nbase = wn*64;
    f32x4 acc[4][4] = {};

    for (int kt = 0; kt < 2; ++kt) {
        if (kt) __syncthreads();
#pragma unroll
        for (int i = 0; i < 4; ++i) {
            int c = tid + i*256;
            int row = c >> 3, seg = c & 7;
            *(uint4*)&As[row*LDSK + seg*8] =
                *(const uint4*)(xb + (long)(m0 + row)*F_IN + kt*64 + seg*8);
        }
#pragma unroll
        for (int i = 0; i < 4; ++i) {
            int c = tid + i*256;
            int row = c >> 3, seg = c & 7;
            *(uint4*)&Bs[row*LDSK + seg*8] =
                *(const uint4*)(wc + (long)(n0 + row)*F_IN + kt*64 + seg*8);
        }
        __syncthreads();
#pragma unroll
        for (int ks = 0; ks < 2; ++ks) {
            const int ko = ks*32 + quad*8;
            bf16x8 af[4], bfr[4];
#pragma unroll
            for (int mi = 0; mi < 4; ++mi)
                af[mi] = *(const bf16x8*)&As[(mbase + mi*16 + l15)*LDSK + ko];
#pragma unroll
            for (int ni = 0; ni < 4; ++ni)
                bfr[ni] = *(const bf16x8*)&Bs[(nbase + ni*16 + l15)*LDSK + ko];
#pragma unroll
            for (int mi = 0; mi < 4; ++mi)
#pragma unroll
                for (int ni = 0; ni < 4; ++ni)
                    acc[mi][ni] = __builtin_amdgcn_mfma_f32_16x16x32_bf16(
                        af[mi], bfr[ni], acc[mi][ni], 0, 0, 0);
        }
    }

    if (n0 < DM) {
#pragma unroll
        for (int mi = 0; mi < 4; ++mi) {
            const int mrow = m0 + mbase + mi*16 + quad*4;
#pragma unroll
            for (int ni = 0; ni < 4; ++ni) {
                const int col = n0 + nbase + ni*16 + l15;
#pragma unroll
                for (int r = 0; r < 4; ++r) {
                    float v = acc[mi][ni][r];
                    xl [(long)(mrow + r)*DM + col] = v;
                    xlb[(long)(mrow + r)*DM + col] = f2bf(v);
                }
            }
        }
    } else {
        const int coloff = n0 - DM;
#pragma unroll
        for (int mi = 0; mi < 4; ++mi) {
            const int mrow = m0 + mbase + mi*16 + quad*4;
#pragma unroll
            for (int ni = 0; ni < 4; ++ni) {
                const int col = coloff + nbase + ni*16 + l15;
#pragma unroll
                for (int r = 0; r < 4; ++r)
                    resid[(long)(mrow + r)*OUTC + col] = (_Float16)acc[mi][ni][r];
            }
        }
    }
}

// ---------------- CSR-bucket build: one thread per edge ----------------
// bucket4 entry: {nA, nB, g, type} -> node kernel needs no edge arrays.
__global__ __launch_bounds__(256) void build_kernel(
        const int* __restrict__ ei, const int* __restrict__ bi,
        int* __restrict__ counts, int4* __restrict__ bucket4) {
    const int e = blockIdx.x*256 + threadIdx.x;
    if (e >= ET) return;
    int nA, nB, tp;
    edge_decode(e, ei, bi, nA, nB, tp);
    const int dst = (tp == 0) ? nB : nA;
    const int fs  = (tp == 0) ? nA : nB;
    const int g   = ei[fs];   // bug-faithful: x_src[full_src] == xr[src_bond[full_src]]
    int slot = atomicAdd(&counts[dst], 1);
    if (slot < CAP) bucket4[(long)dst*CAP + slot] = make_int4(nA, nB, g, tp);
}

// ---------------- fused per-node kernel -------------------------------------
// One block per node. Phase 1: scores for the node's bucket edges (one wave
// per edge, bf16 endpoint rows). Phase 2: per-(node,ch) LOCAL-max softmax
// (softmax is shift-invariant -> identical alpha to the reference's
// global-max version, numerically more stable). Phase 3: aggregation over
// f32 xl rows with raw-exp weights, scaled once by inv; + f16 resid + bias
// + PReLU -> single out write.
__global__ __launch_bounds__(256) void node_kernel(
        const float* __restrict__ xl, const ushort* __restrict__ xlb,
        const float* __restrict__ pe, const float* __restrict__ datt,
        const int* __restrict__ counts, const int4* __restrict__ bucket4,
        const _Float16* __restrict__ resid, const float* __restrict__ bias,
        const float* __restrict__ pw, float* __restrict__ out) {
    __shared__ float s_sc[CAP][32];   // scores, then raw exp weights
    __shared__ int   s_g[CAP];
    __shared__ float s_inv[32];

    const int n = blockIdx.x;
    const int t = threadIdx.x;
    const int l = t & 63, wv = t >> 6;
    const int cnt = min(counts[n], CAP);

    // ---- phase 1: scores ----
    {
        const int pos = l * 4;            // col within 256-wide row
        const int h8 = l >> 3, dq = l & 7;
        float4 pe4[4], w4[4];
#pragma unroll
        for (int c = 0; c < 4; ++c) {
            pe4[c] = *(const float4*)(pe + c*DM + pos);
            w4[c]  = *(const float4*)(datt + (c*H_HEADS + h8)*D_DIM + dq*4);
        }
        for (int i = wv; i < cnt; i += 4) {
            const int4 ed = bucket4[(long)n*CAP + i];   // {nA, nB, g, tp}
            if (l == 0) s_g[i] = ed.z;
            const int tp = ed.w;
            ushort4 ua = *(const ushort4*)(xlb + (long)ed.x*DM + pos);
            ushort4 ub = *(const ushort4*)(xlb + (long)ed.y*DM + pos);
            float sx = bf2f(ua.x) + bf2f(ub.x);
            float sy = bf2f(ua.y) + bf2f(ub.y);
            float sz = bf2f(ua.z) + bf2f(ub.z);
            float sw = bf2f(ua.w) + bf2f(ub.w);

            float p[4];
#pragma unroll
            for (int c = 0; c < 4; ++c) {
                int cB = (tp == 0) ? c : (tp == 1 ? (c+1 < 3 ? c+1 : 3)
                                                  : (c-1 > 0 ? c-1 : 0));
                bool z = (tp == 1 && c == 3) || (tp == 2 && c == 0);
                float4 pa = pe4[c];
                float4 pb = (cB == 0) ? pe4[0] : (cB == 1) ? pe4[1]
                           : (cB == 2) ? pe4[2] : pe4[3];
                float v0 = leaky(sx + pa.x + pb.x);
                float v1 = leaky(sy + pa.y + pb.y);
                float v2 = leaky(sz + pa.z + pb.z);
                float v3 = leaky(sw + pa.w + pb.w);
                float d = w4[c].x*v0 + w4[c].y*v1 + w4[c].z*v2 + w4[c].w*v3;
                p[c] = z ? 0.f : d;
                p[c] += __shfl_xor(p[c], 1);
                p[c] += __shfl_xor(p[c], 2);
                p[c] += __shfl_xor(p[c], 4);
            }
            if (dq < 4) {
                float val = (dq == 0) ? p[0] : (dq == 1) ? p[1]
                           : (dq == 2) ? p[2] : p[3];
                s_sc[i][dq*8 + h8] = val;
            }
        }
    }
    __syncthreads();

    // ---- phase 2: local-max softmax per ch (lanes 0..31 of wave 0) ----
    if (t < 32) {
        float m = -1e30f;
        for (int i = 0; i < cnt; ++i) m = fmaxf(m, s_sc[i][t]);
        float den = 0.f;
        for (int i = 0; i < cnt; ++i) {
            float v = __expf(s_sc[i][t] - m);
            s_sc[i][t] = v;           // raw exp weight
            den += v;
        }
        s_inv[t] = 1.f / (den + 1e-16f);
    }
    __syncthreads();

    // ---- phase 3: aggregation + residual + bias + PReLU ----
    const int ch = t >> 3;
    const int d0 = (t & 7) * 4;
    const int hh = ch & 7, cc = ch >> 3;
    const int dmoff = hh*D_DIM + d0;
    const int col = ch*D_DIM + d0;

    // hoisted independent loads
    const f16x4 hv = *(const f16x4*)(resid + (long)n*OUTC + col);
    const float4 b = *(const float4*)(bias + col);
    const float w = *pw;
    const float4 pv = *(const float4*)(pe + cc*DM + dmoff);

    float4 acc = make_float4(0.f, 0.f, 0.f, 0.f);
    float asum = 0.f;
    for (int i = 0; i < cnt; ++i) {
        float a = s_sc[i][ch];
        int g = s_g[i];
        float4 xv = *(const float4*)(xl + (long)g*DM + dmoff);
        acc.x += a*xv.x; acc.y += a*xv.y; acc.z += a*xv.z; acc.w += a*xv.w;
        asum += a;
    }
    const float inv = s_inv[ch];
    float r0 = (acc.x + asum*pv.x)*inv + (float)hv.x + b.x;
    float r1 = (acc.y + asum*pv.y)*inv + (float)hv.y + b.y;
    float r2 = (acc.z + asum*pv.z)*inv + (float)hv.z + b.z;
    float r3 = (acc.w + asum*pv.w)*inv + (float)hv.w + b.w;
    r0 = r0 >= 0.f ? r0 : w*r0;
    r1 = r1 >= 0.f ? r1 : w*r1;
    r2 = r2 >= 0.f ? r2 : w*r2;
    r3 = r3 >= 0.f ? r3 : w*r3;
    *(float4*)(out + (long)n*OUTC + col) = make_float4(r0, r1, r2, r3);
}

extern "C" void kernel_launch(void* const* d_in, const int* in_sizes, int n_in,
                              void* d_out, int out_size, void* d_ws, size_t ws_size,
                              hipStream_t stream) {
    const float* x     = (const float*)d_in[0];
    const int*   ei    = (const int*)d_in[1];
    const int*   bi    = (const int*)d_in[2];
    const float* W_in  = (const float*)d_in[3];
    const float* datt  = (const float*)d_in[4];
    const float* W_res = (const float*)d_in[5];
    const float* bias  = (const float*)d_in[6];
    const float* pw    = (const float*)d_in[7];
    float* out = (float*)d_out;
    char*  ws  = (char*)d_ws;

    float*     xl      = (float*)(ws + WS_XL);
    ushort*    xlb     = (ushort*)(ws + WS_XLB);
    float*     pe      = (float*)(ws + WS_PE);
    int4*      bucket4 = (int4*)(ws + WS_BUCKET);
    int*       counts  = (int*)(ws + WS_CNT);
    _Float16*  resid   = (_Float16*)(ws + WS_RESID);
    ushort*    xb      = (ushort*)(ws + WS_XB);
    ushort*    wc      = (ushort*)(ws + WS_WC);

    hipMemsetAsync(counts, 0, (size_t)N_NODES*4, stream);
    pe_init_kernel<<<1, 1024, 0, stream>>>(pe);
    cvt_x_kernel<<<(N_NODES*F_IN/4)/256, 256, 0, stream>>>(x, xb);
    cvt_w_kernel<<<(NCOLS*F_IN/4 + 255)/256, 256, 0, stream>>>(W_in, W_res, wc);
    build_kernel<<<(ET+255)/256, 256, 0, stream>>>(ei, bi, counts, bucket4);
    {
        dim3 grid(N_NODES/128, NCOLS/128);   // 256 x 10
        mfma_gemm<<<grid, 256, 0, stream>>>(xb, wc, xl, xlb, resid);
    }
    node_kernel<<<N_NODES, 256, 0, stream>>>(xl, xlb, pe, datt, counts, bucket4,
                                             resid, bias, pw, out);
}

// Round 5
// 321.710 us; speedup vs baseline: 1.2921x; 1.2921x over previous
//
#include <hip/hip_runtime.h>
#include <math.h>

#define N_NODES 32768
#define F_IN    128
#define C_CH    4
#define H_HEADS 8
#define D_DIM   32
#define DM      256
#define E_BOND  65536
#define B_BRIDGE 8192
#define ET      (E_BOND + 2*B_BRIDGE)   // 81920
#define OUTC    1024                    // C*H*D
#define CAP     24                      // bucket capacity per dst node
#define NCOLS   1280                    // DM + OUTC combined bf16 weight rows

// ---- workspace layout (bytes) ----
#define WS_XL      0u                   // N*DM*4      = 33,554,432 (f32)
#define WS_PE      33554432u            // C*DM*4      = 4,096
#define WS_SCORES  33558528u            // ET*32*4     = 10,485,760
#define WS_BUCKET2 44044288u            // N*CAP*8     = 6,291,456  (int2: e, g)
#define WS_CNT     50335744u            // N*4         = 131,072
#define WS_GMAX    50466816u            // 4 (+pad)
#define WS_RESID   50470912u            // N*OUTC*2    = 67,108,864 (f16 residual)
#define WS_XB      117579776u           // N*128*2     = 8,388,608
#define WS_WC      125968384u           // NCOLS*128*2 = 327,680 -> end ~126.3 MB

typedef __attribute__((ext_vector_type(8))) short bf16x8;
typedef __attribute__((ext_vector_type(4))) float f32x4;
typedef __attribute__((ext_vector_type(4))) _Float16 f16x4;

__device__ __forceinline__ unsigned enc_f32(float f) {
    unsigned u = __float_as_uint(f);
    return (u & 0x80000000u) ? ~u : (u | 0x80000000u);
}
__device__ __forceinline__ float dec_f32(unsigned u) {
    return (u & 0x80000000u) ? __uint_as_float(u & 0x7fffffffu) : __uint_as_float(~u);
}
__device__ __forceinline__ float leaky(float v) { return v >= 0.f ? v : 0.2f*v; }
__device__ __forceinline__ ushort f2bf(float f) {
    unsigned u = __float_as_uint(f);
    unsigned r = (u + 0x7fffu + ((u >> 16) & 1u)) >> 16;   // RNE
    return (ushort)r;
}

// decode edge e -> endpoints (nA,nB) and type
__device__ __forceinline__ void edge_decode(int e, const int* __restrict__ ei,
                                            const int* __restrict__ bi,
                                            int& nA, int& nB, int& tp) {
    if (e < E_BOND)               { nA = ei[e]; nB = ei[E_BOND + e]; tp = 0; }
    else if (e < E_BOND+B_BRIDGE) { int i = e - E_BOND;
                                    nA = bi[B_BRIDGE + i]; nB = bi[i]; tp = 1; }
    else                          { int i = e - E_BOND - B_BRIDGE;
                                    nA = bi[i]; nB = bi[B_BRIDGE + i]; tp = 2; }
}

// ---------------- pe + gmax init ----------------
__global__ void pe_init_kernel(float* __restrict__ pe, unsigned* __restrict__ gmax) {
    int tid = threadIdx.x;              // 1024
    int c = tid >> 8, p = tid & 255;
    float expo = (float)(p & ~1) * (1.0f/256.0f);
    float div  = powf(10000.0f, expo);
    float arg  = (float)c / div;
    pe[tid] = (p & 1) ? cosf(arg) : sinf(arg);
    if (tid == 0) *gmax = 0u;
}

// ---------------- fp32 -> bf16 converts ----------------
__global__ __launch_bounds__(256) void cvt_x_kernel(const float* __restrict__ x,
                                                    ushort* __restrict__ xb) {
    const long i = (long)blockIdx.x*256 + threadIdx.x;    // float4 index
    float4 v = ((const float4*)x)[i];
    ushort4 o; o.x = f2bf(v.x); o.y = f2bf(v.y); o.z = f2bf(v.z); o.w = f2bf(v.w);
    ((ushort4*)xb)[i] = o;
}
__global__ __launch_bounds__(256) void cvt_w_kernel(const float* __restrict__ W_in,
                                                    const float* __restrict__ W_res,
                                                    ushort* __restrict__ wc) {
    const int i = blockIdx.x*256 + threadIdx.x;           // float4 index, 40960 total
    float4 v = (i < 8192) ? ((const float4*)W_in)[i] : ((const float4*)W_res)[i - 8192];
    ushort4 o; o.x = f2bf(v.x); o.y = f2bf(v.y); o.z = f2bf(v.z); o.w = f2bf(v.w);
    ((ushort4*)wc)[i] = o;
}

// ---------------- combined MFMA GEMM over 1280 cols ----------------
// cols [0,256)   -> xl (f32)     = x @ W_in^T
// cols [256,1280)-> resid (f16)  = x @ W_res^T
#define LDSK 72   // 64 + 8 pad (bf16)
__global__ __launch_bounds__(256) void mfma_gemm(
        const ushort* __restrict__ xb, const ushort* __restrict__ wc,
        float* __restrict__ xl, _Float16* __restrict__ resid) {
    __shared__ ushort As[128*LDSK];
    __shared__ ushort Bs[128*LDSK];
    const int tid = threadIdx.x;
    const int m0 = blockIdx.x * 128;
    const int n0 = blockIdx.y * 128;
    const int lane = tid & 63, wv = tid >> 6;
    const int wm = wv & 1, wn = wv >> 1;
    const int quad = lane >> 4, l15 = lane & 15;
    const int mbase = wm*64, nbase = wn*64;
    f32x4 acc[4][4] = {};

    for (int kt = 0; kt < 2; ++kt) {
        if (kt) __syncthreads();
#pragma unroll
        for (int i = 0; i < 4; ++i) {
            int c = tid + i*256;
            int row = c >> 3, seg = c & 7;
            *(uint4*)&As[row*LDSK + seg*8] =
                *(const uint4*)(xb + (long)(m0 + row)*F_IN + kt*64 + seg*8);
        }
#pragma unroll
        for (int i = 0; i < 4; ++i) {
            int c = tid + i*256;
            int row = c >> 3, seg = c & 7;
            *(uint4*)&Bs[row*LDSK + seg*8] =
                *(const uint4*)(wc + (long)(n0 + row)*F_IN + kt*64 + seg*8);
        }
        __syncthreads();
#pragma unroll
        for (int ks = 0; ks < 2; ++ks) {
            const int ko = ks*32 + quad*8;
            bf16x8 af[4], bfr[4];
#pragma unroll
            for (int mi = 0; mi < 4; ++mi)
                af[mi] = *(const bf16x8*)&As[(mbase + mi*16 + l15)*LDSK + ko];
#pragma unroll
            for (int ni = 0; ni < 4; ++ni)
                bfr[ni] = *(const bf16x8*)&Bs[(nbase + ni*16 + l15)*LDSK + ko];
#pragma unroll
            for (int mi = 0; mi < 4; ++mi)
#pragma unroll
                for (int ni = 0; ni < 4; ++ni)
                    acc[mi][ni] = __builtin_amdgcn_mfma_f32_16x16x32_bf16(
                        af[mi], bfr[ni], acc[mi][ni], 0, 0, 0);
        }
    }

    if (n0 < DM) {
#pragma unroll
        for (int mi = 0; mi < 4; ++mi) {
            const int mrow = m0 + mbase + mi*16 + quad*4;
#pragma unroll
            for (int ni = 0; ni < 4; ++ni) {
                const int col = n0 + nbase + ni*16 + l15;
#pragma unroll
                for (int r = 0; r < 4; ++r)
                    xl[(long)(mrow + r)*DM + col] = acc[mi][ni][r];
            }
        }
    } else {
        const int coloff = n0 - DM;
#pragma unroll
        for (int mi = 0; mi < 4; ++mi) {
            const int mrow = m0 + mbase + mi*16 + quad*4;
#pragma unroll
            for (int ni = 0; ni < 4; ++ni) {
                const int col = coloff + nbase + ni*16 + l15;
#pragma unroll
                for (int r = 0; r < 4; ++r)
                    resid[(long)(mrow + r)*OUTC + col] = (_Float16)acc[mi][ni][r];
            }
        }
    }
}

// ---------------- CSR-bucket build: one thread per edge ----------------
__global__ __launch_bounds__(256) void build_kernel(
        const int* __restrict__ ei, const int* __restrict__ bi,
        int* __restrict__ counts, int2* __restrict__ bucket2) {
    const int e = blockIdx.x*256 + threadIdx.x;
    if (e >= ET) return;
    int nA, nB, tp;
    edge_decode(e, ei, bi, nA, nB, tp);
    const int dst = (tp == 0) ? nB : nA;
    const int fs  = (tp == 0) ? nA : nB;
    const int g   = ei[fs];   // bug-faithful: x_src[full_src] == xr[src_bond[full_src]]
    int slot = atomicAdd(&counts[dst], 1);
    if (slot < CAP) bucket2[dst*CAP + slot] = make_int2(e, g);
}

// ---------------- scores: one wave per 8 edges, 4-edge unrolled (f32) -------
// lane l owns cols [4l,4l+4) of the 256-wide row: h = l>>3, dq = l&7
__global__ __launch_bounds__(256) void scores_kernel(
        const float* __restrict__ xl, const float* __restrict__ pe,
        const int* __restrict__ ei, const int* __restrict__ bi,
        const float* __restrict__ datt, float* __restrict__ scores,
        unsigned* __restrict__ gmax) {
    const int tid = threadIdx.x;
    const int l = tid & 63, wv = tid >> 6;
    const int pos = l * 4;
    const int h = l >> 3, dq = l & 7;

    float4 pe4[4], w4[4];
#pragma unroll
    for (int c = 0; c < 4; ++c) {
        pe4[c] = *(const float4*)(pe + c*DM + pos);
        w4[c]  = *(const float4*)(datt + (c*H_HEADS + h)*D_DIM + dq*4);
    }

    float wmax = -1e30f;
    const int wavebase = (blockIdx.x*4 + wv) * 8;   // 2560 blocks * 4 waves * 8 = ET
#pragma unroll
    for (int gdx = 0; gdx < 2; ++gdx) {
        const int e0 = wavebase + gdx*4;
        int nA[4], nB[4], tp[4];
#pragma unroll
        for (int j = 0; j < 4; ++j)
            edge_decode(e0 + j, ei, bi, nA[j], nB[j], tp[j]);
        // issue all 8 independent row loads before any math
        float4 ua[4], ub[4];
#pragma unroll
        for (int j = 0; j < 4; ++j) {
            ua[j] = *(const float4*)(xl + (long)nA[j]*DM + pos);
            ub[j] = *(const float4*)(xl + (long)nB[j]*DM + pos);
        }
#pragma unroll
        for (int j = 0; j < 4; ++j) {
            const int e = e0 + j, t = tp[j];
            float sx = ua[j].x + ub[j].x;
            float sy = ua[j].y + ub[j].y;
            float sz = ua[j].z + ub[j].z;
            float sw = ua[j].w + ub[j].w;

            float p[4];
#pragma unroll
            for (int c = 0; c < 4; ++c) {
                int cB = (t == 0) ? c : (t == 1 ? (c+1 < 3 ? c+1 : 3)
                                               : (c-1 > 0 ? c-1 : 0));
                bool z = (t == 1 && c == 3) || (t == 2 && c == 0);
                float4 pa = pe4[c];
                float4 pb = (cB == 0) ? pe4[0] : (cB == 1) ? pe4[1]
                           : (cB == 2) ? pe4[2] : pe4[3];
                float v0 = leaky(sx + pa.x + pb.x);
                float v1 = leaky(sy + pa.y + pb.y);
                float v2 = leaky(sz + pa.z + pb.z);
                float v3 = leaky(sw + pa.w + pb.w);
                float d = w4[c].x*v0 + w4[c].y*v1 + w4[c].z*v2 + w4[c].w*v3;
                p[c] = z ? 0.f : d;
                p[c] += __shfl_xor(p[c], 1);
                p[c] += __shfl_xor(p[c], 2);
                p[c] += __shfl_xor(p[c], 4);
            }
            float val = (dq == 0) ? p[0] : (dq == 1) ? p[1] : (dq == 2) ? p[2] : p[3];
            if (dq < 4) scores[(long)e*32 + dq*8 + h] = val;
            wmax = fmaxf(wmax, fmaxf(fmaxf(p[0], p[1]), fmaxf(p[2], p[3])));
        }
    }

    wmax = fmaxf(wmax, __shfl_xor(wmax, 8));
    wmax = fmaxf(wmax, __shfl_xor(wmax, 16));
    wmax = fmaxf(wmax, __shfl_xor(wmax, 32));
    __shared__ float sm[4];
    if (l == 0) sm[wv] = wmax;
    __syncthreads();
    if (tid == 0) {
        float mm = fmaxf(fmaxf(sm[0], sm[1]), fmaxf(sm[2], sm[3]));
        atomicMax(gmax, enc_f32(mm));
    }
}

// ---------------- gather: SINGLE PASS softmax-aggregate + resid + PReLU -----
// out_agg = (sum_e e^(s_e-m) * x_e) / (den + 1e-16), den = sum_e e^(s_e-m)
// with m = global max -> identical to reference alpha math, but no alpha
// materialization and only ONE walk over the bucket.
// one block per node; thread t owns (ch = t>>3, d-quad = t&7) -> 4 floats.
__global__ __launch_bounds__(256) void gather_kernel(
        const float* __restrict__ xl, const float* __restrict__ pe,
        const float* __restrict__ scores, const int* __restrict__ counts,
        const int2* __restrict__ bucket2, const _Float16* __restrict__ resid,
        const unsigned* __restrict__ gmax, const float* __restrict__ bias,
        const float* __restrict__ pw, float* __restrict__ out) {
    const int n = blockIdx.x;
    const int t = threadIdx.x;
    const int ch = t >> 3;
    const int d0 = (t & 7) * 4;
    const int h = ch & 7, c = ch >> 3;
    const int cnt = min(counts[n], CAP);
    const int col = ch*D_DIM + d0;
    const int nb = n*CAP;
    const float m = dec_f32(*gmax);

    // hoisted independent loads
    const f16x4 hv = *(const f16x4*)(resid + (long)n*OUTC + col);
    const float4 b = *(const float4*)(bias + col);
    const float w = *pw;
    const float4 pv = *(const float4*)(pe + c*DM + h*D_DIM + d0);

    float4 acc = make_float4(0.f, 0.f, 0.f, 0.f);
    float esum = 0.f;

    for (int i0 = 0; i0 < cnt; i0 += 4) {
        int2 eg[4]; bool vld[4];
#pragma unroll
        for (int j = 0; j < 4; ++j) {
            const int idx = i0 + j;
            const int safe = idx < cnt ? idx : i0;      // i0 valid: loop entered
            eg[j] = bucket2[nb + safe];
            vld[j] = idx < cnt;
        }
        float sc[4];
#pragma unroll
        for (int j = 0; j < 4; ++j)
            sc[j] = scores[(long)eg[j].x*32 + ch];
        float4 xv[4];
#pragma unroll
        for (int j = 0; j < 4; ++j)
            xv[j] = *(const float4*)(xl + (long)eg[j].y*DM + h*D_DIM + d0);
#pragma unroll
        for (int j = 0; j < 4; ++j) {
            float ex = vld[j] ? __expf(sc[j] - m) : 0.f;
            acc.x += ex*xv[j].x; acc.y += ex*xv[j].y;
            acc.z += ex*xv[j].z; acc.w += ex*xv[j].w;
            esum += ex;
        }
    }
    const float inv = 1.f / (esum + 1e-16f);

    float r0 = (acc.x + esum*pv.x)*inv + (float)hv.x + b.x;
    float r1 = (acc.y + esum*pv.y)*inv + (float)hv.y + b.y;
    float r2 = (acc.z + esum*pv.z)*inv + (float)hv.z + b.z;
    float r3 = (acc.w + esum*pv.w)*inv + (float)hv.w + b.w;
    r0 = r0 >= 0.f ? r0 : w*r0;
    r1 = r1 >= 0.f ? r1 : w*r1;
    r2 = r2 >= 0.f ? r2 : w*r2;
    r3 = r3 >= 0.f ? r3 : w*r3;
    *(float4*)(out + (long)n*OUTC + col) = make_float4(r0, r1, r2, r3);
}

extern "C" void kernel_launch(void* const* d_in, const int* in_sizes, int n_in,
                              void* d_out, int out_size, void* d_ws, size_t ws_size,
                              hipStream_t stream) {
    const float* x     = (const float*)d_in[0];
    const int*   ei    = (const int*)d_in[1];
    const int*   bi    = (const int*)d_in[2];
    const float* W_in  = (const float*)d_in[3];
    const float* datt  = (const float*)d_in[4];
    const float* W_res = (const float*)d_in[5];
    const float* bias  = (const float*)d_in[6];
    const float* pw    = (const float*)d_in[7];
    float* out = (float*)d_out;
    char*  ws  = (char*)d_ws;

    float*     xl      = (float*)(ws + WS_XL);
    float*     pe      = (float*)(ws + WS_PE);
    float*     scores  = (float*)(ws + WS_SCORES);
    int2*      bucket2 = (int2*)(ws + WS_BUCKET2);
    int*       counts  = (int*)(ws + WS_CNT);
    unsigned*  gmax    = (unsigned*)(ws + WS_GMAX);
    _Float16*  resid   = (_Float16*)(ws + WS_RESID);
    ushort*    xb      = (ushort*)(ws + WS_XB);
    ushort*    wc      = (ushort*)(ws + WS_WC);

    hipMemsetAsync(counts, 0, (size_t)N_NODES*4, stream);
    pe_init_kernel<<<1, 1024, 0, stream>>>(pe, gmax);
    cvt_x_kernel<<<(N_NODES*F_IN/4)/256, 256, 0, stream>>>(x, xb);
    cvt_w_kernel<<<(NCOLS*F_IN/4 + 255)/256, 256, 0, stream>>>(W_in, W_res, wc);
    build_kernel<<<(ET+255)/256, 256, 0, stream>>>(ei, bi, counts, bucket2);
    {
        dim3 grid(N_NODES/128, NCOLS/128);   // 256 x 10
        mfma_gemm<<<grid, 256, 0, stream>>>(xb, wc, xl, resid);
    }
    scores_kernel<<<2560, 256, 0, stream>>>(xl, pe, ei, bi, datt, scores, gmax);
    gather_kernel<<<N_NODES, 256, 0, stream>>>(xl, pe, scores, counts, bucket2,
                                               resid, gmax, bias, pw, out);
}

// Round 6
// 320.721 us; speedup vs baseline: 1.2961x; 1.0031x over previous
//
#include <hip/hip_runtime.h>
#include <math.h>

#define N_NODES 32768
#define F_IN    128
#define C_CH    4
#define H_HEADS 8
#define D_DIM   32
#define DM      256
#define E_BOND  65536
#define B_BRIDGE 8192
#define ET      (E_BOND + 2*B_BRIDGE)   // 81920
#define OUTC    1024                    // C*H*D
#define CAP     24                      // bucket capacity per dst node
#define NCOLS   1280                    // DM + OUTC combined bf16 weight rows

// ---- workspace layout (bytes) ----
#define WS_XL      0u                   // N*DM*4      = 33,554,432 (f32)
#define WS_PE      33554432u            // C*DM*4      = 4,096
#define WS_SCORES  33558528u            // ET*32*4     = 10,485,760
#define WS_BUCKET2 44044288u            // N*CAP*8     = 6,291,456  (int2: e, g)
#define WS_CNT     50335744u            // N*4         = 131,072
#define WS_GMAX    50466816u            // 4 (+pad)
#define WS_RESID   50470912u            // N*OUTC*2    = 67,108,864 (f16 residual)
#define WS_XB      117579776u           // N*128*2     = 8,388,608
#define WS_WC      125968384u           // NCOLS*128*2 = 327,680 -> end ~126.3 MB

typedef __attribute__((ext_vector_type(8))) short bf16x8;
typedef __attribute__((ext_vector_type(4))) float f32x4;
typedef __attribute__((ext_vector_type(4))) _Float16 f16x4;

__device__ __forceinline__ unsigned enc_f32(float f) {
    unsigned u = __float_as_uint(f);
    return (u & 0x80000000u) ? ~u : (u | 0x80000000u);
}
__device__ __forceinline__ float dec_f32(unsigned u) {
    return (u & 0x80000000u) ? __uint_as_float(u & 0x7fffffffu) : __uint_as_float(~u);
}
__device__ __forceinline__ float leaky(float v) { return v >= 0.f ? v : 0.2f*v; }
__device__ __forceinline__ ushort f2bf(float f) {
    unsigned u = __float_as_uint(f);
    unsigned r = (u + 0x7fffu + ((u >> 16) & 1u)) >> 16;   // RNE
    return (ushort)r;
}

// decode edge e -> endpoints (nA,nB) and type
__device__ __forceinline__ void edge_decode(int e, const int* __restrict__ ei,
                                            const int* __restrict__ bi,
                                            int& nA, int& nB, int& tp) {
    if (e < E_BOND)               { nA = ei[e]; nB = ei[E_BOND + e]; tp = 0; }
    else if (e < E_BOND+B_BRIDGE) { int i = e - E_BOND;
                                    nA = bi[B_BRIDGE + i]; nB = bi[i]; tp = 1; }
    else                          { int i = e - E_BOND - B_BRIDGE;
                                    nA = bi[i]; nB = bi[B_BRIDGE + i]; tp = 2; }
}

// =========================== K0: prep ======================================
// heterogeneous: [0,4096) cvt_x | [4096,4256) cvt_w | [4256,4576) build |
//                4576 pe+gmax init.  All branches independent.
__global__ __launch_bounds__(256) void prep_kernel(
        const float* __restrict__ x, const float* __restrict__ W_in,
        const float* __restrict__ W_res, const int* __restrict__ ei,
        const int* __restrict__ bi, ushort* __restrict__ xb,
        ushort* __restrict__ wc, int* __restrict__ counts,
        int2* __restrict__ bucket2, float* __restrict__ pe,
        unsigned* __restrict__ gmax) {
    const int bid = blockIdx.x;
    const int tid = threadIdx.x;
    if (bid < 4096) {                       // ---- cvt_x ----
        const long i = (long)bid*256 + tid;             // float4 index
        float4 v = ((const float4*)x)[i];
        ushort4 o; o.x = f2bf(v.x); o.y = f2bf(v.y); o.z = f2bf(v.z); o.w = f2bf(v.w);
        ((ushort4*)xb)[i] = o;
    } else if (bid < 4256) {                // ---- cvt_w ----
        const int i = (bid - 4096)*256 + tid;           // float4 index, 40960 total
        float4 v = (i < 8192) ? ((const float4*)W_in)[i]
                              : ((const float4*)W_res)[i - 8192];
        ushort4 o; o.x = f2bf(v.x); o.y = f2bf(v.y); o.z = f2bf(v.z); o.w = f2bf(v.w);
        ((ushort4*)wc)[i] = o;
    } else if (bid < 4576) {                // ---- build ----
        const int e = (bid - 4256)*256 + tid;
        if (e < ET) {
            int nA, nB, tp;
            edge_decode(e, ei, bi, nA, nB, tp);
            const int dst = (tp == 0) ? nB : nA;
            const int fs  = (tp == 0) ? nA : nB;
            const int g   = ei[fs];   // bug-faithful: x_src[full_src] == xr[src_bond[...]]
            int slot = atomicAdd(&counts[dst], 1);
            if (slot < CAP) bucket2[dst*CAP + slot] = make_int2(e, g);
        }
    } else {                                // ---- pe + gmax ----
#pragma unroll
        for (int k = 0; k < 4; ++k) {
            int idx = k*256 + tid;
            int c = idx >> 8, p = idx & 255;
            float expo = (float)(p & ~1) * (1.0f/256.0f);
            float div  = powf(10000.0f, expo);
            float arg  = (float)c / div;
            pe[idx] = (p & 1) ? cosf(arg) : sinf(arg);
        }
        if (tid == 0) *gmax = 0u;
    }
}

// =========================== K1: xl GEMM ===================================
// xl[m,n] = sum_k xb[m,k]*W_in[n,k]  (wc rows [0,256))
#define LDSK 72   // 64 + 8 pad (bf16)
__global__ __launch_bounds__(256) void gemm_xl_kernel(
        const ushort* __restrict__ xb, const ushort* __restrict__ wc,
        float* __restrict__ xl) {
    __shared__ ushort As[128*LDSK];
    __shared__ ushort Bs[128*LDSK];
    const int tid = threadIdx.x;
    const int m0 = (blockIdx.x & 255) * 128;
    const int n0 = (blockIdx.x >> 8) * 128;     // 0 or 128
    const int lane = tid & 63, wv = tid >> 6;
    const int wm = wv & 1, wn = wv >> 1;
    const int quad = lane >> 4, l15 = lane & 15;
    const int mbase = wm*64, nbase = wn*64;
    f32x4 acc[4][4] = {};

    for (int kt = 0; kt < 2; ++kt) {
        if (kt) __syncthreads();
#pragma unroll
        for (int i = 0; i < 4; ++i) {
            int c = tid + i*256;
            int row = c >> 3, seg = c & 7;
            *(uint4*)&As[row*LDSK + seg*8] =
                *(const uint4*)(xb + (long)(m0 + row)*F_IN + kt*64 + seg*8);
        }
#pragma unroll
        for (int i = 0; i < 4; ++i) {
            int c = tid + i*256;
            int row = c >> 3, seg = c & 7;
            *(uint4*)&Bs[row*LDSK + seg*8] =
                *(const uint4*)(wc + (long)(n0 + row)*F_IN + kt*64 + seg*8);
        }
        __syncthreads();
#pragma unroll
        for (int ks = 0; ks < 2; ++ks) {
            const int ko = ks*32 + quad*8;
            bf16x8 af[4], bfr[4];
#pragma unroll
            for (int mi = 0; mi < 4; ++mi)
                af[mi] = *(const bf16x8*)&As[(mbase + mi*16 + l15)*LDSK + ko];
#pragma unroll
            for (int ni = 0; ni < 4; ++ni)
                bfr[ni] = *(const bf16x8*)&Bs[(nbase + ni*16 + l15)*LDSK + ko];
#pragma unroll
            for (int mi = 0; mi < 4; ++mi)
#pragma unroll
                for (int ni = 0; ni < 4; ++ni)
                    acc[mi][ni] = __builtin_amdgcn_mfma_f32_16x16x32_bf16(
                        af[mi], bfr[ni], acc[mi][ni], 0, 0, 0);
        }
    }

#pragma unroll
    for (int mi = 0; mi < 4; ++mi) {
        const int mrow = m0 + mbase + mi*16 + quad*4;
#pragma unroll
        for (int ni = 0; ni < 4; ++ni) {
            const int col = n0 + nbase + ni*16 + l15;
#pragma unroll
            for (int r = 0; r < 4; ++r)
                xl[(long)(mrow + r)*DM + col] = acc[mi][ni][r];
        }
    }
}

// =========================== K2: resid GEMM || scores ======================
// 4608 blocks; per 9 consecutive blocks: 5 scores + 4 gemm (interleaved so
// MFMA-bound gemm waves co-schedule with latency-bound scores waves, m114).
__global__ __launch_bounds__(256) void mix_kernel(
        const ushort* __restrict__ xb, const ushort* __restrict__ wc,
        _Float16* __restrict__ resid,
        const float* __restrict__ xl, const float* __restrict__ pe,
        const int* __restrict__ ei, const int* __restrict__ bi,
        const float* __restrict__ datt, float* __restrict__ scores,
        unsigned* __restrict__ gmax) {
    __shared__ ushort As[128*LDSK];
    __shared__ ushort Bs[128*LDSK];
    __shared__ float sm4[4];
    const int tid = threadIdx.x;
    const int grp = blockIdx.x / 9, r9 = blockIdx.x % 9;
    const int lane = tid & 63, wv = tid >> 6;

    if (r9 >= 5) {
        // ---------------- resid GEMM block ----------------
        const int gb = grp*4 + (r9 - 5);            // 0..2047
        const int m0 = (gb >> 3) * 128;
        const int coloff = (gb & 7) * 128;
        const int wm = wv & 1, wn = wv >> 1;
        const int quad = lane >> 4, l15 = lane & 15;
        const int mbase = wm*64, nbase = wn*64;
        f32x4 acc[4][4] = {};

        for (int kt = 0; kt < 2; ++kt) {
            if (kt) __syncthreads();
#pragma unroll
            for (int i = 0; i < 4; ++i) {
                int c = tid + i*256;
                int row = c >> 3, seg = c & 7;
                *(uint4*)&As[row*LDSK + seg*8] =
                    *(const uint4*)(xb + (long)(m0 + row)*F_IN + kt*64 + seg*8);
            }
#pragma unroll
            for (int i = 0; i < 4; ++i) {
                int c = tid + i*256;
                int row = c >> 3, seg = c & 7;
                *(uint4*)&Bs[row*LDSK + seg*8] =
                    *(const uint4*)(wc + (long)(DM + coloff + row)*F_IN + kt*64 + seg*8);
            }
            __syncthreads();
#pragma unroll
            for (int ks = 0; ks < 2; ++ks) {
                const int ko = ks*32 + quad*8;
                bf16x8 af[4], bfr[4];
#pragma unroll
                for (int mi = 0; mi < 4; ++mi)
                    af[mi] = *(const bf16x8*)&As[(mbase + mi*16 + l15)*LDSK + ko];
#pragma unroll
                for (int ni = 0; ni < 4; ++ni)
                    bfr[ni] = *(const bf16x8*)&Bs[(nbase + ni*16 + l15)*LDSK + ko];
#pragma unroll
                for (int mi = 0; mi < 4; ++mi)
#pragma unroll
                    for (int ni = 0; ni < 4; ++ni)
                        acc[mi][ni] = __builtin_amdgcn_mfma_f32_16x16x32_bf16(
                            af[mi], bfr[ni], acc[mi][ni], 0, 0, 0);
            }
        }
#pragma unroll
        for (int mi = 0; mi < 4; ++mi) {
            const int mrow = m0 + mbase + mi*16 + quad*4;
#pragma unroll
            for (int ni = 0; ni < 4; ++ni) {
                const int col = coloff + nbase + ni*16 + l15;
#pragma unroll
                for (int rr = 0; rr < 4; ++rr)
                    resid[(long)(mrow + rr)*OUTC + col] = (_Float16)acc[mi][ni][rr];
            }
        }
    } else {
        // ---------------- scores block (wave per 8 edges, 4-unrolled) ------
        const int sb = grp*5 + r9;                  // 0..2559
        const int pos = lane * 4;
        const int h = lane >> 3, dq = lane & 7;

        float4 pe4[4], w4[4];
#pragma unroll
        for (int c = 0; c < 4; ++c) {
            pe4[c] = *(const float4*)(pe + c*DM + pos);
            w4[c]  = *(const float4*)(datt + (c*H_HEADS + h)*D_DIM + dq*4);
        }

        float wmax = -1e30f;
        const int wavebase = (sb*4 + wv) * 8;       // 2560*4*8 = ET
#pragma unroll
        for (int gdx = 0; gdx < 2; ++gdx) {
            const int e0 = wavebase + gdx*4;
            int nA[4], nB[4], tp[4];
#pragma unroll
            for (int j = 0; j < 4; ++j)
                edge_decode(e0 + j, ei, bi, nA[j], nB[j], tp[j]);
            float4 ua[4], ub[4];
#pragma unroll
            for (int j = 0; j < 4; ++j) {
                ua[j] = *(const float4*)(xl + (long)nA[j]*DM + pos);
                ub[j] = *(const float4*)(xl + (long)nB[j]*DM + pos);
            }
#pragma unroll
            for (int j = 0; j < 4; ++j) {
                const int e = e0 + j, t = tp[j];
                float sx = ua[j].x + ub[j].x;
                float sy = ua[j].y + ub[j].y;
                float sz = ua[j].z + ub[j].z;
                float sw = ua[j].w + ub[j].w;

                float p[4];
#pragma unroll
                for (int c = 0; c < 4; ++c) {
                    int cB = (t == 0) ? c : (t == 1 ? (c+1 < 3 ? c+1 : 3)
                                                   : (c-1 > 0 ? c-1 : 0));
                    bool z = (t == 1 && c == 3) || (t == 2 && c == 0);
                    float4 pa = pe4[c];
                    float4 pb = (cB == 0) ? pe4[0] : (cB == 1) ? pe4[1]
                               : (cB == 2) ? pe4[2] : pe4[3];
                    float v0 = leaky(sx + pa.x + pb.x);
                    float v1 = leaky(sy + pa.y + pb.y);
                    float v2 = leaky(sz + pa.z + pb.z);
                    float v3 = leaky(sw + pa.w + pb.w);
                    float d = w4[c].x*v0 + w4[c].y*v1 + w4[c].z*v2 + w4[c].w*v3;
                    p[c] = z ? 0.f : d;
                    p[c] += __shfl_xor(p[c], 1);
                    p[c] += __shfl_xor(p[c], 2);
                    p[c] += __shfl_xor(p[c], 4);
                }
                float val = (dq == 0) ? p[0] : (dq == 1) ? p[1]
                           : (dq == 2) ? p[2] : p[3];
                if (dq < 4) scores[(long)e*32 + dq*8 + h] = val;
                wmax = fmaxf(wmax, fmaxf(fmaxf(p[0], p[1]), fmaxf(p[2], p[3])));
            }
        }

        wmax = fmaxf(wmax, __shfl_xor(wmax, 8));
        wmax = fmaxf(wmax, __shfl_xor(wmax, 16));
        wmax = fmaxf(wmax, __shfl_xor(wmax, 32));
        if (lane == 0) sm4[wv] = wmax;
        __syncthreads();
        if (tid == 0) {
            float mm = fmaxf(fmaxf(sm4[0], sm4[1]), fmaxf(sm4[2], sm4[3]));
            atomicMax(gmax, enc_f32(mm));
        }
    }
}

// =========================== K3: gather ====================================
// single-pass softmax-aggregate + f16 resid + bias + PReLU (proven R5 form)
__global__ __launch_bounds__(256) void gather_kernel(
        const float* __restrict__ xl, const float* __restrict__ pe,
        const float* __restrict__ scores, const int* __restrict__ counts,
        const int2* __restrict__ bucket2, const _Float16* __restrict__ resid,
        const unsigned* __restrict__ gmax, const float* __restrict__ bias,
        const float* __restrict__ pw, float* __restrict__ out) {
    const int n = blockIdx.x;
    const int t = threadIdx.x;
    const int ch = t >> 3;
    const int d0 = (t & 7) * 4;
    const int h = ch & 7, c = ch >> 3;
    const int cnt = min(counts[n], CAP);
    const int col = ch*D_DIM + d0;
    const int nb = n*CAP;
    const float m = dec_f32(*gmax);

    const f16x4 hv = *(const f16x4*)(resid + (long)n*OUTC + col);
    const float4 b = *(const float4*)(bias + col);
    const float w = *pw;
    const float4 pv = *(const float4*)(pe + c*DM + h*D_DIM + d0);

    float4 acc = make_float4(0.f, 0.f, 0.f, 0.f);
    float esum = 0.f;

    for (int i0 = 0; i0 < cnt; i0 += 4) {
        int2 eg[4]; bool vld[4];
#pragma unroll
        for (int j = 0; j < 4; ++j) {
            const int idx = i0 + j;
            const int safe = idx < cnt ? idx : i0;
            eg[j] = bucket2[nb + safe];
            vld[j] = idx < cnt;
        }
        float sc[4];
#pragma unroll
        for (int j = 0; j < 4; ++j)
            sc[j] = scores[(long)eg[j].x*32 + ch];
        float4 xv[4];
#pragma unroll
        for (int j = 0; j < 4; ++j)
            xv[j] = *(const float4*)(xl + (long)eg[j].y*DM + h*D_DIM + d0);
#pragma unroll
        for (int j = 0; j < 4; ++j) {
            float ex = vld[j] ? __expf(sc[j] - m) : 0.f;
            acc.x += ex*xv[j].x; acc.y += ex*xv[j].y;
            acc.z += ex*xv[j].z; acc.w += ex*xv[j].w;
            esum += ex;
        }
    }
    const float inv = 1.f / (esum + 1e-16f);

    float r0 = (acc.x + esum*pv.x)*inv + (float)hv.x + b.x;
    float r1 = (acc.y + esum*pv.y)*inv + (float)hv.y + b.y;
    float r2 = (acc.z + esum*pv.z)*inv + (float)hv.z + b.z;
    float r3 = (acc.w + esum*pv.w)*inv + (float)hv.w + b.w;
    r0 = r0 >= 0.f ? r0 : w*r0;
    r1 = r1 >= 0.f ? r1 : w*r1;
    r2 = r2 >= 0.f ? r2 : w*r2;
    r3 = r3 >= 0.f ? r3 : w*r3;
    *(float4*)(out + (long)n*OUTC + col) = make_float4(r0, r1, r2, r3);
}

extern "C" void kernel_launch(void* const* d_in, const int* in_sizes, int n_in,
                              void* d_out, int out_size, void* d_ws, size_t ws_size,
                              hipStream_t stream) {
    const float* x     = (const float*)d_in[0];
    const int*   ei    = (const int*)d_in[1];
    const int*   bi    = (const int*)d_in[2];
    const float* W_in  = (const float*)d_in[3];
    const float* datt  = (const float*)d_in[4];
    const float* W_res = (const float*)d_in[5];
    const float* bias  = (const float*)d_in[6];
    const float* pw    = (const float*)d_in[7];
    float* out = (float*)d_out;
    char*  ws  = (char*)d_ws;

    float*     xl      = (float*)(ws + WS_XL);
    float*     pe      = (float*)(ws + WS_PE);
    float*     scores  = (float*)(ws + WS_SCORES);
    int2*      bucket2 = (int2*)(ws + WS_BUCKET2);
    int*       counts  = (int*)(ws + WS_CNT);
    unsigned*  gmax    = (unsigned*)(ws + WS_GMAX);
    _Float16*  resid   = (_Float16*)(ws + WS_RESID);
    ushort*    xb      = (ushort*)(ws + WS_XB);
    ushort*    wc      = (ushort*)(ws + WS_WC);

    hipMemsetAsync(counts, 0, (size_t)N_NODES*4, stream);
    prep_kernel<<<4577, 256, 0, stream>>>(x, W_in, W_res, ei, bi, xb, wc,
                                          counts, bucket2, pe, gmax);
    gemm_xl_kernel<<<512, 256, 0, stream>>>(xb, wc, xl);
    mix_kernel<<<4608, 256, 0, stream>>>(xb, wc, resid, xl, pe, ei, bi, datt,
                                         scores, gmax);
    gather_kernel<<<N_NODES, 256, 0, stream>>>(xl, pe, scores, counts, bucket2,
                                               resid, gmax, bias, pw, out);
}